// Round 6
// baseline (459.254 us; speedup 1.0000x reference)
//
#include <hip/hip_runtime.h>
#include <math.h>

#define TPB 256

struct SP {
    int  n;               // number of scales covered by this launch
    int  blkBase[13];     // cumulative block offsets per scale
    int  xBase[13];       // cumulative hs (flattened horizontal output index)
    int  hs[12];          // resized (square) image size
    int  ph[12];          // pooled size = ceil((hs-2)/2)
    int  istr[12];        // padded row stride (floats) for tmp2/img rows = align4(hs*3)
    int  wstr[12];        // fixed tap count per scale = ceil(2*inv)+2
    float inv[12];        // 1080/hs  (jax inv_scale, fp32 of double)
    float rinv[12];       // hs/1080  (reciprocal, for weight eval)
    float scl[12];        // detection scale (fp32 of double) for boxes
    long wOff[12];        // normalized weight table [wstr][hs] offset (floats)
    long jOff[12];        // jlo table [hs] offset (int slots)
    long tmpOff[12];      // tmp2 (h-resized, [4,1080,istr]) offset (floats)
    long imgOff[12];      // final image ([4,hs,istr]) offset
    long pOff[12];        // pool output offset
    long qOff[12];        // conv2 output offset
    long base[12];        // row offset into N
};

__device__ __forceinline__ float lrelu(float x) { return x > 0.f ? x : 0.3f * x; }

__device__ __forceinline__ int find_scale(const SP& p, int bb) {
    int s = 0;
#pragma unroll
    for (int k = 1; k < 12; k++)
        if (k < p.n && bb >= p.blkBase[k]) s = k;
    return s;
}

// Stage 0: per-scale normalized triangle-resample weight tables (used by vres2).
__global__ __launch_bounds__(TPB) void k_wt(float* __restrict__ wsb, SP p) {
    int s = blockIdx.x;
    int hs = p.hs[s];
    int wstr = p.wstr[s];
    float inv = p.inv[s], rinv = p.rinv[s];
    float* wt = wsb + p.wOff[s];
    int* jt = (int*)wsb + p.jOff[s];
    for (int x = threadIdx.x; x < hs; x += TPB) {
        float c = ((float)x + 0.5f) * inv - 0.5f;
        int jlo = (int)floorf(c - inv);
        if (jlo < 0) jlo = 0;
        if (jlo > 1080 - wstr) jlo = 1080 - wstr;
        float sum = 0.f;
        for (int k = 0; k < wstr; k++) {
            float w = fmaxf(0.f, 1.f - fabsf(c - (float)(jlo + k)) * rinv);
            sum += w;
        }
        float rt = 1.f / sum;
        for (int k = 0; k < wstr; k++) {
            float w = fmaxf(0.f, 1.f - fabsf(c - (float)(jlo + k)) * rinv);
            wt[k * hs + x] = w * rt;
        }
        jt[x] = jlo;
    }
}

// Stage 1: horizontal resize for ALL scales, flattened (scale,x) work index.
__global__ __launch_bounds__(TPB) void k_hres1(const float* __restrict__ in,
                                               float* __restrict__ wsb, SP p) {
    __shared__ float row[3240];
    __shared__ float sInv[12], sRinv[12];
    __shared__ int sWstr[12], sXB[13];
    __shared__ long sOff[12];
    int r = blockIdx.x;               // r = b*1080 + j
    if (threadIdx.x < 12) {
        int s = threadIdx.x;
        if (s < p.n) {
            sInv[s] = p.inv[s];
            sRinv[s] = p.rinv[s];
            sWstr[s] = p.wstr[s];
            sXB[s] = p.xBase[s];
            sOff[s] = p.tmpOff[s] + (long)r * p.istr[s];
        }
    }
    if (threadIdx.x == 0) sXB[p.n] = p.xBase[p.n];
    const float4* src = (const float4*)(in + (long)r * 3240);
    float4* row4 = (float4*)row;
    for (int ch = threadIdx.x; ch < 810; ch += TPB) row4[ch] = src[ch];
    __syncthreads();
    int xTot = p.xBase[p.n];
    for (int ft = threadIdx.x; ft < xTot; ft += TPB) {
        int s = 0;
#pragma unroll
        for (int k = 1; k < 12; k++)
            if (k < p.n && ft >= sXB[k]) s = k;
        int x = ft - sXB[s];
        float inv = sInv[s], rinv = sRinv[s];
        int wstr = sWstr[s];
        float c = ((float)x + 0.5f) * inv - 0.5f;
        int jlo = (int)floorf(c - inv);
        if (jlo < 0) jlo = 0;
        int jmax = 1080 - wstr;
        if (jlo > jmax) jlo = jmax;
        float d = c - (float)jlo;          // decreases by 1 per tap
        const float* pr = row + jlo * 3;
        float n0 = 0.f, n1 = 0.f, n2 = 0.f, tw = 0.f;
        for (int k = 0; k < wstr; k++) {
            float w = fmaxf(0.f, fmaf(-fabsf(d), rinv, 1.f));
            tw += w;
            n0 += w * pr[0]; n1 += w * pr[1]; n2 += w * pr[2];
            d -= 1.f; pr += 3;
        }
        float rt = 1.f / tw;
        float* o = wsb + sOff[s] + x * 3;
        o[0] = n0 * rt;
        o[1] = n1 * rt;
        o[2] = n2 * rt;
    }
}

// Stage 2: vertical resize per scale + affine, weights from table.
__global__ __launch_bounds__(TPB) void k_vres2(float* __restrict__ wsb, SP p) {
    __shared__ float wsm[152];
    int bb = blockIdx.x;
    int s = find_scale(p, bb);
    int hs = p.hs[s];
    int istr = p.istr[s];
    int wstr = p.wstr[s];
    int r = bb - p.blkBase[s];        // r = b*hs + i
    int i = r % hs;
    int b = r / hs;
    int jlo = ((const int*)wsb + p.jOff[s])[i];
    const float* wt = wsb + p.wOff[s];
    for (int k = threadIdx.x; k < wstr; k += TPB)
        wsm[k] = wt[k * hs + i];
    __syncthreads();
    int W4 = istr >> 2;
    const float4* src0 = (const float4*)(wsb + p.tmpOff[s] + ((long)b * 1080 + jlo) * istr);
    float4* dst = (float4*)(wsb + p.imgOff[s] + (long)r * istr);
    for (int ch = threadIdx.x; ch < W4; ch += TPB) {
        float4 acc = {0.f, 0.f, 0.f, 0.f};
        const float4* sp = src0 + ch;
        for (int k = 0; k < wstr; k++) {
            float w = wsm[k];
            float4 v = sp[(long)k * W4];
            acc.x += w * v.x; acc.y += w * v.y; acc.z += w * v.z; acc.w += w * v.w;
        }
        float4 o;
        o.x = (acc.x - 127.5f) * 0.0078125f;
        o.y = (acc.y - 127.5f) * 0.0078125f;
        o.z = (acc.z - 127.5f) * 0.0078125f;
        o.w = (acc.w - 127.5f) * 0.0078125f;
        dst[ch] = o;
    }
}

// Stage 3: conv1(3x3x3->10, VALID) + lrelu + maxpool 2x2 stride2 SAME
__global__ __launch_bounds__(TPB) void k_c1p(float* __restrict__ wsb,
                                             const float* __restrict__ w1,
                                             const float* __restrict__ b1, SP p) {
    int bb = blockIdx.x;
    int s = find_scale(p, bb);
    int hs = p.hs[s];
    int istr = p.istr[s];
    int ph = p.ph[s];
    int t = (bb - p.blkBase[s]) * TPB + threadIdx.x;
    if (t >= 4 * ph * ph) return;
    int px = t % ph;
    int rem = t / ph;
    int pi = rem % ph;
    int b = rem / ph;
    const float* img = wsb + p.imgOff[s] + (long)b * hs * istr;
    int r0 = 2 * pi, c0 = 2 * px;
    float im[4][4][3];
#pragma unroll
    for (int dy = 0; dy < 4; dy++) {
        int r = r0 + dy;
#pragma unroll
        for (int dx = 0; dx < 4; dx++) {
            int cc = c0 + dx;
            if (r < hs && cc < hs) {
                const float* pp = img + (long)r * istr + cc * 3;
                im[dy][dx][0] = pp[0]; im[dy][dx][1] = pp[1]; im[dy][dx][2] = pp[2];
            } else {
                im[dy][dx][0] = 0.f; im[dy][dx][1] = 0.f; im[dy][dx][2] = 0.f;
            }
        }
    }
    int ch = hs - 2;                  // conv1 output size
    bool v01 = (c0 + 1) < ch;         // SAME pool: partial last window
    bool v10 = (r0 + 1) < ch;
    bool v11 = v01 && v10;
    float* P = wsb + p.pOff[s] + (((long)b * ph + pi) * ph + px) * 10;
#pragma unroll 1
    for (int oc = 0; oc < 10; ++oc) {
        float bias = b1[oc];
        float a00 = bias, a01 = bias, a10 = bias, a11 = bias;
#pragma unroll
        for (int ky = 0; ky < 3; ky++)
#pragma unroll
            for (int kx = 0; kx < 3; kx++)
#pragma unroll
                for (int ic = 0; ic < 3; ic++) {
                    float w = w1[((ky * 3 + kx) * 3 + ic) * 10 + oc];
                    a00 += im[ky][kx][ic] * w;
                    a01 += im[ky][kx + 1][ic] * w;
                    a10 += im[ky + 1][kx][ic] * w;
                    a11 += im[ky + 1][kx + 1][ic] * w;
                }
        float mx = lrelu(a00);
        if (v01) mx = fmaxf(mx, lrelu(a01));
        if (v10) mx = fmaxf(mx, lrelu(a10));
        if (v11) mx = fmaxf(mx, lrelu(a11));
        P[oc] = mx;
    }
}

// Stage 4: conv2(3x3x10->16, VALID) + lrelu — 2x2 output tile per thread.
__global__ __launch_bounds__(TPB) void k_c2(float* __restrict__ wsb,
                                            const float* __restrict__ w2,
                                            const float* __restrict__ b2, SP p) {
    int bb = blockIdx.x;
    int s = find_scale(p, bb);
    int ph = p.ph[s];
    int qh = ph - 2;
    int qhx = (qh + 1) >> 1;
    int t = (bb - p.blkBase[s]) * TPB + threadIdx.x;
    if (t >= 4 * qhx * qhx) return;
    int qxt = t % qhx;
    int rem = t / qhx;
    int qyt = rem % qhx;
    int b = rem / qhx;
    int qx = 2 * qxt, qy = 2 * qyt;
    bool vx = (qx + 1) < qh, vy = (qy + 1) < qh;
    const float* P = wsb + p.pOff[s] + (long)b * ph * ph * 10;
    float acc[4][16];
#pragma unroll
    for (int oc = 0; oc < 16; oc++) {
        float bv = b2[oc];
        acc[0][oc] = bv; acc[1][oc] = bv; acc[2][oc] = bv; acc[3][oc] = bv;
    }
#pragma unroll 1
    for (int ky = 0; ky < 4; ky++) {
        int rr = qy + ky; if (rr > ph - 1) rr = ph - 1;
        const float* rowp = P + (long)rr * ph * 10;
        float pix[4][10];
#pragma unroll
        for (int ci = 0; ci < 4; ci++) {
            int cc = qx + ci; if (cc > ph - 1) cc = ph - 1;
            const float2* pp = (const float2*)(rowp + cc * 10);
#pragma unroll
            for (int h = 0; h < 5; h++) {
                float2 v2 = pp[h];
                pix[ci][2 * h] = v2.x; pix[ci][2 * h + 1] = v2.y;
            }
        }
        if (ky <= 2) {                // contributes to output row qy (kernel row ky)
            int pos0 = ky * 3;
#pragma unroll
            for (int kx = 0; kx < 3; kx++)
#pragma unroll
                for (int ic = 0; ic < 10; ic++)
#pragma unroll
                    for (int oc = 0; oc < 16; oc++) {
                        float w = w2[((pos0 + kx) * 10 + ic) * 16 + oc];
                        acc[0][oc] += pix[kx][ic] * w;
                        acc[1][oc] += pix[kx + 1][ic] * w;
                    }
        }
        if (ky >= 1) {                // contributes to output row qy+1 (kernel row ky-1)
            int pos0 = (ky - 1) * 3;
#pragma unroll
            for (int kx = 0; kx < 3; kx++)
#pragma unroll
                for (int ic = 0; ic < 10; ic++)
#pragma unroll
                    for (int oc = 0; oc < 16; oc++) {
                        float w = w2[((pos0 + kx) * 10 + ic) * 16 + oc];
                        acc[2][oc] += pix[kx][ic] * w;
                        acc[3][oc] += pix[kx + 1][ic] * w;
                    }
        }
    }
    float* Qb = wsb + p.qOff[s] + (long)b * qh * qh * 16;
#pragma unroll
    for (int oy = 0; oy < 2; oy++) {
#pragma unroll
        for (int ox = 0; ox < 2; ox++) {
            if ((oy == 1 && !vy) || (ox == 1 && !vx)) continue;
            float4* Q4 = (float4*)(Qb + ((long)(qy + oy) * qh + (qx + ox)) * 16);
            const float* a = acc[oy * 2 + ox];
#pragma unroll
            for (int h = 0; h < 4; h++) {
                float4 o;
                o.x = lrelu(a[4 * h + 0]); o.y = lrelu(a[4 * h + 1]);
                o.z = lrelu(a[4 * h + 2]); o.w = lrelu(a[4 * h + 3]);
                Q4[h] = o;
            }
        }
    }
}

__device__ __forceinline__ void ldcol16(float v[16], const float* q) {
#pragma unroll
    for (int h = 0; h < 4; h++) {
        float4 t4 = ((const float4*)q)[h];
        v[4 * h] = t4.x; v[4 * h + 1] = t4.y; v[4 * h + 2] = t4.z; v[4 * h + 3] = t4.w;
    }
}

__device__ __forceinline__ void mac32(float acc[32], const float v[16],
                                      const float* __restrict__ w3, int pos) {
#pragma unroll
    for (int ic = 0; ic < 16; ic++)
#pragma unroll
        for (int oc = 0; oc < 32; oc++)
            acc[oc] += v[ic] * w3[(pos * 16 + ic) * 32 + oc];
}

__device__ __forceinline__ void head_store(const float acc[32],
                                           const float* __restrict__ wp, const float* __restrict__ bpb,
                                           const float* __restrict__ wr, const float* __restrict__ brb,
                                           float* __restrict__ out, long N, long g,
                                           float sclf, float fy, float fx) {
    float p0 = bpb[0], p1 = bpb[1];
    float r0 = brb[0], r1 = brb[1], r2 = brb[2], r3 = brb[3];
#pragma unroll
    for (int ic = 0; ic < 32; ic++) {
        float v = lrelu(acc[ic]);
        p0 += v * wp[ic * 2 + 0]; p1 += v * wp[ic * 2 + 1];
        r0 += v * wr[ic * 4 + 0]; r1 += v * wr[ic * 4 + 1];
        r2 += v * wr[ic * 4 + 2]; r3 += v * wr[ic * 4 + 3];
    }
    float mx = fmaxf(p0, p1);
    float e0 = expf(p0 - mx), e1 = expf(p1 - mx);
    float score = e1 / (e0 + e1);
    float* ob = out + g * 5;
    ob[0] = rintf((2.f * fy + 1.f) / sclf);
    ob[1] = rintf((2.f * fx + 1.f) / sclf);
    ob[2] = rintf((2.f * fy + 12.f) / sclf);
    ob[3] = rintf((2.f * fx + 12.f) / sclf);
    ob[4] = score;
    float* orr = out + N * 20 + g * 4;
    orr[0] = r0; orr[1] = r1; orr[2] = r2; orr[3] = r3;
    out[N * 36 + g] = (score >= 0.6f) ? 1.f : 0.f;
}

// Stage 5: conv3(3x3x16->32) + lrelu + heads — 1x2 output tile per thread,
// rolling 2-column register reuse (ca/cb) inside each kernel row.
__global__ __launch_bounds__(TPB) void k_c3h(float* __restrict__ wsb,
                                             const float* __restrict__ w3,
                                             const float* __restrict__ b3,
                                             const float* __restrict__ wp,
                                             const float* __restrict__ bpb,
                                             const float* __restrict__ wr,
                                             const float* __restrict__ brb,
                                             float* __restrict__ out, long N, SP p) {
    int bb = blockIdx.x;
    int s = find_scale(p, bb);
    int ph = p.ph[s];
    int qh = ph - 2;
    int oh = ph - 4;
    int ohx = (oh + 1) >> 1;
    int t = (bb - p.blkBase[s]) * TPB + threadIdx.x;
    if (t >= 4 * oh * ohx) return;
    int xt = t % ohx;
    int rem = t / ohx;
    int y = rem % oh;
    int b = rem / oh;
    int x = 2 * xt;
    bool vx = (x + 1) < oh;
    const float* Q = wsb + p.qOff[s] + (long)b * qh * qh * 16;
    float acc0[32], acc1[32];
#pragma unroll
    for (int oc = 0; oc < 32; oc++) { float bv = b3[oc]; acc0[oc] = bv; acc1[oc] = bv; }
#pragma unroll 1
    for (int ky = 0; ky < 3; ky++) {
        const float* rowp = Q + (long)(y + ky) * qh * 16;
        int c3i = x + 3; if (c3i > qh - 1) c3i = qh - 1;
        float ca[16], cb[16];
        ldcol16(ca, rowp + (long)x * 16);
        ldcol16(cb, rowp + (long)(x + 1) * 16);
        int pos = ky * 3;
        mac32(acc0, ca, w3, pos);     mac32(acc1, cb, w3, pos);
        ldcol16(ca, rowp + (long)(x + 2) * 16);
        mac32(acc0, cb, w3, pos + 1); mac32(acc1, ca, w3, pos + 1);
        ldcol16(cb, rowp + (long)c3i * 16);
        mac32(acc0, ca, w3, pos + 2); mac32(acc1, cb, w3, pos + 2);
    }
    float sclf = p.scl[s];
    long idx = p.base[s] + (long)y * oh + x;
    long g = (long)b * N + idx;
    head_store(acc0, wp, bpb, wr, brb, out, N, g, sclf, (float)y, (float)x);
    if (vx)
        head_store(acc1, wp, bpb, wr, brb, out, N, g + 1, sclf, (float)y, (float)(x + 1));
}

static int fill_blocks(SP& q, const int* cnt) {   // thread-count based
    int acc = 0;
    for (int s = 0; s < q.n; s++) {
        q.blkBase[s] = acc;
        acc += (cnt[s] + TPB - 1) / TPB;
    }
    q.blkBase[q.n] = acc;
    return acc;
}

static int fill_rows(SP& q, const int* cnt) {     // one block per row
    int acc = 0;
    for (int s = 0; s < q.n; s++) {
        q.blkBase[s] = acc;
        acc += cnt[s];
    }
    q.blkBase[q.n] = acc;
    return acc;
}

extern "C" void kernel_launch(void* const* d_in, const int* in_sizes, int n_in,
                              void* d_out, int out_size, void* d_ws, size_t ws_size,
                              hipStream_t stream) {
    const float* in = (const float*)d_in[0];
    const float* w1 = (const float*)d_in[1];
    const float* b1 = (const float*)d_in[2];
    const float* w2 = (const float*)d_in[3];
    const float* b2 = (const float*)d_in[4];
    const float* w3 = (const float*)d_in[5];
    const float* b3 = (const float*)d_in[6];
    const float* wp = (const float*)d_in[7];
    const float* bp = (const float*)d_in[8];
    const float* wr = (const float*)d_in[9];
    const float* br = (const float*)d_in[10];
    float* ws = (float*)d_ws;
    float* out = (float*)d_out;

    // scale pyramid — identical double arithmetic to the Python reference
    double sc = 12.0 / 20.0, m = sc * 1080.0;
    int ns = 0;
    double scl[12];
    while (m >= 12.0 && ns < 12) { scl[ns++] = sc; sc *= 0.709; m *= 0.709; }

    int hs[12], ph[12], istr[12], wstr[12];
    long base[12];
    long N = 0;
    for (int s = 0; s < ns; s++) {
        hs[s] = (int)ceil(1080.0 * scl[s]);
        ph[s] = (hs[s] - 1) / 2;               // ceil((hs-2)/2)
        istr[s] = ((hs[s] * 3 + 3) / 4) * 4;   // 16B-aligned row stride
        double invd = 1080.0 / (double)hs[s];
        wstr[s] = (int)ceil(2.0 * invd) + 2;
        if (wstr[s] > 1080) wstr[s] = 1080;
    }
    for (int s = 0; s < ns; s++) {
        int oh = ph[s] - 4;
        base[s] = N;
        N += (long)oh * oh;
    }

    // workspace layout: weight tables first (persist), then stage buffers
    long wOff[12], jOff[12], tmpOff[12], imgOff[12], pOff[12], qOff[12];
    long off = 0;
    for (int s = 0; s < ns; s++) { wOff[s] = off; off += (long)wstr[s] * hs[s]; }
    for (int s = 0; s < ns; s++) { jOff[s] = off; off += hs[s]; }
    off = (off + 3) & ~3L;
    long tabEnd = off;
    for (int s = 0; s < ns; s++) { tmpOff[s] = off; off += 4L * 1080 * istr[s]; }
    for (int s = 0; s < ns; s++) { imgOff[s] = off; off += 4L * hs[s] * istr[s]; }
    for (int s = 0; s < ns; s++) { pOff[s] = off; off += 4L * ph[s] * ph[s] * 10; }
    for (int s = 0; s < ns; s++) { qOff[s] = off; off += 4L * (ph[s] - 2) * (ph[s] - 2) * 16; }
    bool batched = (ws_size >= (size_t)off * 4);
    if (!batched) {
        long TMP2MAX = 4L * 1080 * istr[0];
        long IMGMAX = 4L * hs[0] * istr[0];
        long PMAX = 4L * ph[0] * ph[0] * 10;
        for (int s = 0; s < ns; s++) {
            tmpOff[s] = tabEnd;
            imgOff[s] = tabEnd + TMP2MAX;
            pOff[s] = tabEnd + TMP2MAX + IMGMAX;
            qOff[s] = tabEnd + TMP2MAX + IMGMAX + PMAX;
        }
    }

    // full-pyramid SP for the weight-table kernel
    SP pAll;
    pAll.n = ns;
    for (int s = 0; s < ns; s++) {
        pAll.hs[s] = hs[s]; pAll.ph[s] = ph[s]; pAll.istr[s] = istr[s];
        pAll.wstr[s] = wstr[s];
        pAll.inv[s] = (float)(1080.0 / (double)hs[s]);
        pAll.rinv[s] = (float)((double)hs[s] / 1080.0);
        pAll.scl[s] = (float)scl[s];
        pAll.wOff[s] = wOff[s]; pAll.jOff[s] = jOff[s];
        pAll.tmpOff[s] = tmpOff[s]; pAll.imgOff[s] = imgOff[s];
        pAll.pOff[s] = pOff[s]; pAll.qOff[s] = qOff[s];
        pAll.base[s] = base[s];
    }
    k_wt<<<ns, TPB, 0, stream>>>(ws, pAll);

    int gcount = batched ? 1 : ns;
    for (int g = 0; g < gcount; ++g) {
        int s0 = batched ? 0 : g;
        int cnt = batched ? ns : 1;
        SP p;
        p.n = cnt;
        int xacc = 0;
        for (int k = 0; k < cnt; k++) {
            int s = s0 + k;
            p.hs[k] = hs[s]; p.ph[k] = ph[s]; p.istr[k] = istr[s];
            p.wstr[k] = wstr[s];
            p.xBase[k] = xacc; xacc += hs[s];
            p.inv[k] = (float)(1080.0 / (double)hs[s]);
            p.rinv[k] = (float)((double)hs[s] / 1080.0);
            p.scl[k] = (float)scl[s];
            p.wOff[k] = wOff[s]; p.jOff[k] = jOff[s];
            p.tmpOff[k] = tmpOff[s]; p.imgOff[k] = imgOff[s];
            p.pOff[k] = pOff[s]; p.qOff[k] = qOff[s];
            p.base[k] = base[s];
        }
        p.xBase[cnt] = xacc;
        int crow[12], c3[12], c4[12], c5[12];
        for (int k = 0; k < cnt; k++) {
            int s = s0 + k;
            int PH = ph[s], QH = PH - 2, OH = PH - 4;
            int QHX = (QH + 1) / 2, OHX = (OH + 1) / 2;
            crow[k] = 4 * hs[s];          // output rows for vres2 (block-per-row)
            c3[k] = 4 * PH * PH;
            c4[k] = 4 * QHX * QHX;        // 2x2 tiles
            c5[k] = 4 * OH * OHX;         // 1x2 tiles
        }
        int nb;
        SP ps = p;
        // horizontal (all scales fused via flattened index, row staged in LDS)
        k_hres1<<<4 * 1080, TPB, 0, stream>>>(in, ws, p);
        ps = p; nb = fill_rows(ps, crow);
        k_vres2<<<nb, TPB, 0, stream>>>(ws, ps);
        ps = p; nb = fill_blocks(ps, c3);
        k_c1p<<<nb, TPB, 0, stream>>>(ws, w1, b1, ps);
        ps = p; nb = fill_blocks(ps, c4);
        k_c2<<<nb, TPB, 0, stream>>>(ws, w2, b2, ps);
        ps = p; nb = fill_blocks(ps, c5);
        k_c3h<<<nb, TPB, 0, stream>>>(ws, w3, b3, wp, bp, wr, br, out, N, ps);
    }
}

// Round 7
// 431.858 us; speedup vs baseline: 1.0634x; 1.0634x over previous
//
#include <hip/hip_runtime.h>
#include <math.h>

#define TPB 256
#define C3T 16   // c3h output tile edge

struct SP {
    int  n;               // number of scales covered by this launch
    int  blkBase[13];     // cumulative block offsets per scale
    int  xBase[13];       // cumulative hs (flattened horizontal output index)
    int  hs[12];          // resized (square) image size
    int  ph[12];          // pooled size = ceil((hs-2)/2)
    int  istr[12];        // padded row stride (floats) for tmp2/img rows = align4(hs*3)
    int  wstr[12];        // fixed tap count per scale = ceil(2*inv)+2
    float inv[12];        // 1080/hs  (jax inv_scale, fp32 of double)
    float rinv[12];       // hs/1080  (reciprocal, for weight eval)
    float scl[12];        // detection scale (fp32 of double) for boxes
    long wOff[12];        // normalized weight table [wstr][hs] offset (floats)
    long jOff[12];        // jlo table [hs] offset (int slots)
    long tmpOff[12];      // tmp2 (h-resized, [4,1080,istr]) offset (floats)
    long imgOff[12];      // final image ([4,hs,istr]) offset
    long pOff[12];        // pool output offset
    long qOff[12];        // conv2 output offset
    long base[12];        // row offset into N
};

__device__ __forceinline__ float lrelu(float x) { return x > 0.f ? x : 0.3f * x; }

__device__ __forceinline__ int find_scale(const SP& p, int bb) {
    int s = 0;
#pragma unroll
    for (int k = 1; k < 12; k++)
        if (k < p.n && bb >= p.blkBase[k]) s = k;
    return s;
}

// Stage 0: per-scale normalized triangle-resample weight tables (used by vres2).
__global__ __launch_bounds__(TPB) void k_wt(float* __restrict__ wsb, SP p) {
    int s = blockIdx.x;
    int hs = p.hs[s];
    int wstr = p.wstr[s];
    float inv = p.inv[s], rinv = p.rinv[s];
    float* wt = wsb + p.wOff[s];
    int* jt = (int*)wsb + p.jOff[s];
    for (int x = threadIdx.x; x < hs; x += TPB) {
        float c = ((float)x + 0.5f) * inv - 0.5f;
        int jlo = (int)floorf(c - inv);
        if (jlo < 0) jlo = 0;
        if (jlo > 1080 - wstr) jlo = 1080 - wstr;
        float sum = 0.f;
        for (int k = 0; k < wstr; k++) {
            float w = fmaxf(0.f, 1.f - fabsf(c - (float)(jlo + k)) * rinv);
            sum += w;
        }
        float rt = 1.f / sum;
        for (int k = 0; k < wstr; k++) {
            float w = fmaxf(0.f, 1.f - fabsf(c - (float)(jlo + k)) * rinv);
            wt[k * hs + x] = w * rt;
        }
        jt[x] = jlo;
    }
}

// Stage 1: horizontal resize for ALL scales, flattened (scale,x) work index.
__global__ __launch_bounds__(TPB) void k_hres1(const float* __restrict__ in,
                                               float* __restrict__ wsb, SP p) {
    __shared__ float row[3240];
    __shared__ float sInv[12], sRinv[12];
    __shared__ int sWstr[12], sXB[13];
    __shared__ long sOff[12];
    int r = blockIdx.x;               // r = b*1080 + j
    if (threadIdx.x < 12) {
        int s = threadIdx.x;
        if (s < p.n) {
            sInv[s] = p.inv[s];
            sRinv[s] = p.rinv[s];
            sWstr[s] = p.wstr[s];
            sXB[s] = p.xBase[s];
            sOff[s] = p.tmpOff[s] + (long)r * p.istr[s];
        }
    }
    if (threadIdx.x == 0) sXB[p.n] = p.xBase[p.n];
    const float4* src = (const float4*)(in + (long)r * 3240);
    float4* row4 = (float4*)row;
    for (int ch = threadIdx.x; ch < 810; ch += TPB) row4[ch] = src[ch];
    __syncthreads();
    int xTot = p.xBase[p.n];
    for (int ft = threadIdx.x; ft < xTot; ft += TPB) {
        int s = 0;
#pragma unroll
        for (int k = 1; k < 12; k++)
            if (k < p.n && ft >= sXB[k]) s = k;
        int x = ft - sXB[s];
        float inv = sInv[s], rinv = sRinv[s];
        int wstr = sWstr[s];
        float c = ((float)x + 0.5f) * inv - 0.5f;
        int jlo = (int)floorf(c - inv);
        if (jlo < 0) jlo = 0;
        int jmax = 1080 - wstr;
        if (jlo > jmax) jlo = jmax;
        float d = c - (float)jlo;          // decreases by 1 per tap
        const float* pr = row + jlo * 3;
        float n0 = 0.f, n1 = 0.f, n2 = 0.f, tw = 0.f;
        for (int k = 0; k < wstr; k++) {
            float w = fmaxf(0.f, fmaf(-fabsf(d), rinv, 1.f));
            tw += w;
            n0 += w * pr[0]; n1 += w * pr[1]; n2 += w * pr[2];
            d -= 1.f; pr += 3;
        }
        float rt = 1.f / tw;
        float* o = wsb + sOff[s] + x * 3;
        o[0] = n0 * rt;
        o[1] = n1 * rt;
        o[2] = n2 * rt;
    }
}

// Stage 2: vertical resize per scale + affine, weights from table.
__global__ __launch_bounds__(TPB) void k_vres2(float* __restrict__ wsb, SP p) {
    __shared__ float wsm[152];
    int bb = blockIdx.x;
    int s = find_scale(p, bb);
    int hs = p.hs[s];
    int istr = p.istr[s];
    int wstr = p.wstr[s];
    int r = bb - p.blkBase[s];        // r = b*hs + i
    int i = r % hs;
    int b = r / hs;
    int jlo = ((const int*)wsb + p.jOff[s])[i];
    const float* wt = wsb + p.wOff[s];
    for (int k = threadIdx.x; k < wstr; k += TPB)
        wsm[k] = wt[k * hs + i];
    __syncthreads();
    int W4 = istr >> 2;
    const float4* src0 = (const float4*)(wsb + p.tmpOff[s] + ((long)b * 1080 + jlo) * istr);
    float4* dst = (float4*)(wsb + p.imgOff[s] + (long)r * istr);
    for (int ch = threadIdx.x; ch < W4; ch += TPB) {
        float4 acc = {0.f, 0.f, 0.f, 0.f};
        const float4* sp = src0 + ch;
        for (int k = 0; k < wstr; k++) {
            float w = wsm[k];
            float4 v = sp[(long)k * W4];
            acc.x += w * v.x; acc.y += w * v.y; acc.z += w * v.z; acc.w += w * v.w;
        }
        float4 o;
        o.x = (acc.x - 127.5f) * 0.0078125f;
        o.y = (acc.y - 127.5f) * 0.0078125f;
        o.z = (acc.z - 127.5f) * 0.0078125f;
        o.w = (acc.w - 127.5f) * 0.0078125f;
        dst[ch] = o;
    }
}

// Stage 3: conv1(3x3x3->10, VALID) + lrelu + maxpool 2x2 stride2 SAME
__global__ __launch_bounds__(TPB) void k_c1p(float* __restrict__ wsb,
                                             const float* __restrict__ w1,
                                             const float* __restrict__ b1, SP p) {
    int bb = blockIdx.x;
    int s = find_scale(p, bb);
    int hs = p.hs[s];
    int istr = p.istr[s];
    int ph = p.ph[s];
    int t = (bb - p.blkBase[s]) * TPB + threadIdx.x;
    if (t >= 4 * ph * ph) return;
    int px = t % ph;
    int rem = t / ph;
    int pi = rem % ph;
    int b = rem / ph;
    const float* img = wsb + p.imgOff[s] + (long)b * hs * istr;
    int r0 = 2 * pi, c0 = 2 * px;
    float im[4][4][3];
#pragma unroll
    for (int dy = 0; dy < 4; dy++) {
        int r = r0 + dy;
#pragma unroll
        for (int dx = 0; dx < 4; dx++) {
            int cc = c0 + dx;
            if (r < hs && cc < hs) {
                const float* pp = img + (long)r * istr + cc * 3;
                im[dy][dx][0] = pp[0]; im[dy][dx][1] = pp[1]; im[dy][dx][2] = pp[2];
            } else {
                im[dy][dx][0] = 0.f; im[dy][dx][1] = 0.f; im[dy][dx][2] = 0.f;
            }
        }
    }
    int ch = hs - 2;                  // conv1 output size
    bool v01 = (c0 + 1) < ch;         // SAME pool: partial last window
    bool v10 = (r0 + 1) < ch;
    bool v11 = v01 && v10;
    float* P = wsb + p.pOff[s] + (((long)b * ph + pi) * ph + px) * 10;
#pragma unroll 1
    for (int oc = 0; oc < 10; ++oc) {
        float bias = b1[oc];
        float a00 = bias, a01 = bias, a10 = bias, a11 = bias;
#pragma unroll
        for (int ky = 0; ky < 3; ky++)
#pragma unroll
            for (int kx = 0; kx < 3; kx++)
#pragma unroll
                for (int ic = 0; ic < 3; ic++) {
                    float w = w1[((ky * 3 + kx) * 3 + ic) * 10 + oc];
                    a00 += im[ky][kx][ic] * w;
                    a01 += im[ky][kx + 1][ic] * w;
                    a10 += im[ky + 1][kx][ic] * w;
                    a11 += im[ky + 1][kx + 1][ic] * w;
                }
        float mx = lrelu(a00);
        if (v01) mx = fmaxf(mx, lrelu(a01));
        if (v10) mx = fmaxf(mx, lrelu(a10));
        if (v11) mx = fmaxf(mx, lrelu(a11));
        P[oc] = mx;
    }
}

// Stage 4: conv2(3x3x10->16, VALID) + lrelu — float2 input loads, float4 stores
__global__ __launch_bounds__(TPB) void k_c2(float* __restrict__ wsb,
                                            const float* __restrict__ w2,
                                            const float* __restrict__ b2, SP p) {
    int bb = blockIdx.x;
    int s = find_scale(p, bb);
    int ph = p.ph[s];
    int qh = ph - 2;
    int t = (bb - p.blkBase[s]) * TPB + threadIdx.x;
    if (t >= 4 * qh * qh) return;
    int qx = t % qh;
    int rem = t / qh;
    int qi = rem % qh;
    int b = rem / qh;
    const float* P = wsb + p.pOff[s] + (long)b * ph * ph * 10;
    float acc[16];
#pragma unroll
    for (int oc = 0; oc < 16; oc++) acc[oc] = b2[oc];
#pragma unroll 1
    for (int pos = 0; pos < 9; pos++) {
        int ky = pos / 3, kx = pos - ky * 3;
        const float* pp = P + ((long)(qi + ky) * ph + (qx + kx)) * 10;
        float v[10];
#pragma unroll
        for (int h = 0; h < 5; h++) {
            float2 v2 = *(const float2*)(pp + 2 * h);
            v[2 * h] = v2.x; v[2 * h + 1] = v2.y;
        }
#pragma unroll
        for (int ic = 0; ic < 10; ic++)
#pragma unroll
            for (int oc = 0; oc < 16; oc++)
                acc[oc] += v[ic] * w2[(pos * 10 + ic) * 16 + oc];
    }
    float* Q = wsb + p.qOff[s] + (((long)b * qh + qi) * qh + qx) * 16;
    float4* Q4 = (float4*)Q;
#pragma unroll
    for (int h = 0; h < 4; h++) {
        float4 o;
        o.x = lrelu(acc[4 * h + 0]); o.y = lrelu(acc[4 * h + 1]);
        o.z = lrelu(acc[4 * h + 2]); o.w = lrelu(acc[4 * h + 3]);
        Q4[h] = o;
    }
}

// Stage 5: conv3(3x3x16->32) + lrelu + heads — 16x16 output tile per block,
// Q halo (18x18x16) staged in LDS (column stride 20 floats for bank spread).
__global__ __launch_bounds__(TPB) void k_c3h(float* __restrict__ wsb,
                                             const float* __restrict__ w3,
                                             const float* __restrict__ b3,
                                             const float* __restrict__ wp,
                                             const float* __restrict__ bpb,
                                             const float* __restrict__ wr,
                                             const float* __restrict__ brb,
                                             float* __restrict__ out, long N, SP p) {
    __shared__ float Qs[18 * 18 * 20];
    int bb = blockIdx.x;
    int s = find_scale(p, bb);
    int ph = p.ph[s];
    int qh = ph - 2;
    int oh = ph - 4;
    int ntx = (oh + C3T - 1) / C3T;
    int tile = bb - p.blkBase[s];
    int tx = tile % ntx;
    int rem = tile / ntx;
    int ty = rem % ntx;
    int b = rem / ntx;
    int x0 = tx * C3T, y0 = ty * C3T;
    const float* Q = wsb + p.qOff[s] + (long)b * qh * qh * 16;
    for (int site = threadIdx.x; site < 324; site += TPB) {
        int lr = site / 18, lc = site - lr * 18;
        int gr = y0 + lr; if (gr > qh - 1) gr = qh - 1;
        int gc = x0 + lc; if (gc > qh - 1) gc = qh - 1;
        const float4* srcp = (const float4*)(Q + ((long)gr * qh + gc) * 16);
        float4* dstp = (float4*)&Qs[(lr * 18 + lc) * 20];
#pragma unroll
        for (int h = 0; h < 4; h++) dstp[h] = srcp[h];
    }
    __syncthreads();
    int ox = threadIdx.x & 15, oy = threadIdx.x >> 4;
    int x = x0 + ox, y = y0 + oy;
    float acc[32];
#pragma unroll
    for (int oc = 0; oc < 32; oc++) acc[oc] = b3[oc];
#pragma unroll 1
    for (int pos = 0; pos < 9; pos++) {
        int ky = pos / 3, kx = pos - ky * 3;
        const float4* cp = (const float4*)&Qs[((oy + ky) * 18 + ox + kx) * 20];
        float v[16];
#pragma unroll
        for (int h = 0; h < 4; h++) {
            float4 v4 = cp[h];
            v[4 * h] = v4.x; v[4 * h + 1] = v4.y; v[4 * h + 2] = v4.z; v[4 * h + 3] = v4.w;
        }
#pragma unroll
        for (int ic = 0; ic < 16; ic++)
#pragma unroll
            for (int oc = 0; oc < 32; oc++)
                acc[oc] += v[ic] * w3[(pos * 16 + ic) * 32 + oc];
    }
    if (x >= oh || y >= oh) return;
    float p0 = bpb[0], p1 = bpb[1];
    float r0 = brb[0], r1 = brb[1], r2 = brb[2], r3 = brb[3];
#pragma unroll
    for (int ic = 0; ic < 32; ic++) {
        float v = lrelu(acc[ic]);
        p0 += v * wp[ic * 2 + 0]; p1 += v * wp[ic * 2 + 1];
        r0 += v * wr[ic * 4 + 0]; r1 += v * wr[ic * 4 + 1];
        r2 += v * wr[ic * 4 + 2]; r3 += v * wr[ic * 4 + 3];
    }
    float mx = fmaxf(p0, p1);
    float e0 = expf(p0 - mx), e1 = expf(p1 - mx);
    float score = e1 / (e0 + e1);
    float sclf = p.scl[s];
    long idx = p.base[s] + (long)y * oh + x;
    long g = (long)b * N + idx;
    float fy = (float)y, fx = (float)x;
    float* ob = out + g * 5;
    ob[0] = rintf((2.f * fy + 1.f) / sclf);
    ob[1] = rintf((2.f * fx + 1.f) / sclf);
    ob[2] = rintf((2.f * fy + 12.f) / sclf);
    ob[3] = rintf((2.f * fx + 12.f) / sclf);
    ob[4] = score;
    float* orr = out + N * 20 + g * 4;
    orr[0] = r0; orr[1] = r1; orr[2] = r2; orr[3] = r3;
    out[N * 36 + g] = (score >= 0.6f) ? 1.f : 0.f;
}

static int fill_blocks(SP& q, const int* cnt) {   // thread-count based
    int acc = 0;
    for (int s = 0; s < q.n; s++) {
        q.blkBase[s] = acc;
        acc += (cnt[s] + TPB - 1) / TPB;
    }
    q.blkBase[q.n] = acc;
    return acc;
}

static int fill_rows(SP& q, const int* cnt) {     // one block per row/tile
    int acc = 0;
    for (int s = 0; s < q.n; s++) {
        q.blkBase[s] = acc;
        acc += cnt[s];
    }
    q.blkBase[q.n] = acc;
    return acc;
}

extern "C" void kernel_launch(void* const* d_in, const int* in_sizes, int n_in,
                              void* d_out, int out_size, void* d_ws, size_t ws_size,
                              hipStream_t stream) {
    const float* in = (const float*)d_in[0];
    const float* w1 = (const float*)d_in[1];
    const float* b1 = (const float*)d_in[2];
    const float* w2 = (const float*)d_in[3];
    const float* b2 = (const float*)d_in[4];
    const float* w3 = (const float*)d_in[5];
    const float* b3 = (const float*)d_in[6];
    const float* wp = (const float*)d_in[7];
    const float* bp = (const float*)d_in[8];
    const float* wr = (const float*)d_in[9];
    const float* br = (const float*)d_in[10];
    float* ws = (float*)d_ws;
    float* out = (float*)d_out;

    // scale pyramid — identical double arithmetic to the Python reference
    double sc = 12.0 / 20.0, m = sc * 1080.0;
    int ns = 0;
    double scl[12];
    while (m >= 12.0 && ns < 12) { scl[ns++] = sc; sc *= 0.709; m *= 0.709; }

    int hs[12], ph[12], istr[12], wstr[12];
    long base[12];
    long N = 0;
    for (int s = 0; s < ns; s++) {
        hs[s] = (int)ceil(1080.0 * scl[s]);
        ph[s] = (hs[s] - 1) / 2;               // ceil((hs-2)/2)
        istr[s] = ((hs[s] * 3 + 3) / 4) * 4;   // 16B-aligned row stride
        double invd = 1080.0 / (double)hs[s];
        wstr[s] = (int)ceil(2.0 * invd) + 2;
        if (wstr[s] > 1080) wstr[s] = 1080;
    }
    for (int s = 0; s < ns; s++) {
        int oh = ph[s] - 4;
        base[s] = N;
        N += (long)oh * oh;
    }

    // workspace layout: weight tables first (persist), then stage buffers
    long wOff[12], jOff[12], tmpOff[12], imgOff[12], pOff[12], qOff[12];
    long off = 0;
    for (int s = 0; s < ns; s++) { wOff[s] = off; off += (long)wstr[s] * hs[s]; }
    for (int s = 0; s < ns; s++) { jOff[s] = off; off += hs[s]; }
    off = (off + 3) & ~3L;
    long tabEnd = off;
    for (int s = 0; s < ns; s++) { tmpOff[s] = off; off += 4L * 1080 * istr[s]; }
    for (int s = 0; s < ns; s++) { imgOff[s] = off; off += 4L * hs[s] * istr[s]; }
    for (int s = 0; s < ns; s++) { pOff[s] = off; off += 4L * ph[s] * ph[s] * 10; }
    for (int s = 0; s < ns; s++) { qOff[s] = off; off += 4L * (ph[s] - 2) * (ph[s] - 2) * 16; }
    bool batched = (ws_size >= (size_t)off * 4);
    if (!batched) {
        long TMP2MAX = 4L * 1080 * istr[0];
        long IMGMAX = 4L * hs[0] * istr[0];
        long PMAX = 4L * ph[0] * ph[0] * 10;
        for (int s = 0; s < ns; s++) {
            tmpOff[s] = tabEnd;
            imgOff[s] = tabEnd + TMP2MAX;
            pOff[s] = tabEnd + TMP2MAX + IMGMAX;
            qOff[s] = tabEnd + TMP2MAX + IMGMAX + PMAX;
        }
    }

    // full-pyramid SP for the weight-table kernel
    SP pAll;
    pAll.n = ns;
    for (int s = 0; s < ns; s++) {
        pAll.hs[s] = hs[s]; pAll.ph[s] = ph[s]; pAll.istr[s] = istr[s];
        pAll.wstr[s] = wstr[s];
        pAll.inv[s] = (float)(1080.0 / (double)hs[s]);
        pAll.rinv[s] = (float)((double)hs[s] / 1080.0);
        pAll.scl[s] = (float)scl[s];
        pAll.wOff[s] = wOff[s]; pAll.jOff[s] = jOff[s];
        pAll.tmpOff[s] = tmpOff[s]; pAll.imgOff[s] = imgOff[s];
        pAll.pOff[s] = pOff[s]; pAll.qOff[s] = qOff[s];
        pAll.base[s] = base[s];
    }
    k_wt<<<ns, TPB, 0, stream>>>(ws, pAll);

    int gcount = batched ? 1 : ns;
    for (int g = 0; g < gcount; ++g) {
        int s0 = batched ? 0 : g;
        int cnt = batched ? ns : 1;
        SP p;
        p.n = cnt;
        int xacc = 0;
        for (int k = 0; k < cnt; k++) {
            int s = s0 + k;
            p.hs[k] = hs[s]; p.ph[k] = ph[s]; p.istr[k] = istr[s];
            p.wstr[k] = wstr[s];
            p.xBase[k] = xacc; xacc += hs[s];
            p.inv[k] = (float)(1080.0 / (double)hs[s]);
            p.rinv[k] = (float)((double)hs[s] / 1080.0);
            p.scl[k] = (float)scl[s];
            p.wOff[k] = wOff[s]; p.jOff[k] = jOff[s];
            p.tmpOff[k] = tmpOff[s]; p.imgOff[k] = imgOff[s];
            p.pOff[k] = pOff[s]; p.qOff[k] = qOff[s];
            p.base[k] = base[s];
        }
        p.xBase[cnt] = xacc;
        int crow[12], c3[12], c4[12], c5[12];
        for (int k = 0; k < cnt; k++) {
            int s = s0 + k;
            int PH = ph[s], QH = PH - 2, OH = PH - 4;
            int NTX = (OH + C3T - 1) / C3T;
            crow[k] = 4 * hs[s];          // output rows for vres2 (block-per-row)
            c3[k] = 4 * PH * PH;
            c4[k] = 4 * QH * QH;
            c5[k] = 4 * NTX * NTX;        // 16x16 tiles (block count)
        }
        int nb;
        SP ps = p;
        // horizontal (all scales fused via flattened index, row staged in LDS)
        k_hres1<<<4 * 1080, TPB, 0, stream>>>(in, ws, p);
        ps = p; nb = fill_rows(ps, crow);
        k_vres2<<<nb, TPB, 0, stream>>>(ws, ps);
        ps = p; nb = fill_blocks(ps, c3);
        k_c1p<<<nb, TPB, 0, stream>>>(ws, w1, b1, ps);
        ps = p; nb = fill_blocks(ps, c4);
        k_c2<<<nb, TPB, 0, stream>>>(ws, w2, b2, ps);
        ps = p; nb = fill_rows(ps, c5);
        k_c3h<<<nb, TPB, 0, stream>>>(ws, w3, b3, wp, bp, wr, br, out, N, ps);
    }
}